// Round 7
// baseline (148.268 us; speedup 1.0000x reference)
//
#include <hip/hip_runtime.h>

// BalancedBCEWithLogitsLoss, MI355X (gfx950).  Round 7.
//
// loss = (sum_pos_bce + K * sum_neg_bce / num_neg) / (num_pos + K),
// K = max(3*num_pos, floor(0.05*n)), clamped to num_neg.
// (Population-mean substitution for the reference's random negative sample —
// verified absmax 0.0 in R1-R6.)
//
// R6 post-mortem: logical read rate pinned at 3.15 TB/s across MLP 2-8 and
// occupancy 22-58% == exactly half the 6.3 TB/s copy ceiling, while single-
// stream kernels (RMSNorm m146) reach 4.9 TB/s.  Hypothesis: pred[i] and
// label[i] are a fixed 64 MiB (power-of-2) apart -> both streams hit the
// SAME HBM channel / IC slice at the same instant -> channel aliasing halves
// effective BW.  R7: phase-skewed loads.  Phase A = pred first-half + label
// second-half of the block window; Phase B = the complements.  Concurrent
// pred/label addresses now differ by 4-16 KB (varying), decorrelating the
// channel phase.  Data dependence (no bce pair computable until phase B)
// also forces 16-deep MLP — what R6's compiler refused.  Zero atomics.

#define NB_THREADS 256

__device__ __forceinline__ void bce4(float4 xv, float4 yv,
                                     float& tsum, float& psum, float& csum)
{
    float xs[4] = {xv.x, xv.y, xv.z, xv.w};
    float ys[4] = {yv.x, yv.y, yv.z, yv.w};
#pragma unroll
    for (int j = 0; j < 4; ++j) {
        float xi = xs[j], yi = ys[j];
        // stable BCE: max(x,0) - x*y + log(1+exp(-|x|)), HW v_exp/v_log
        float bce = fmaxf(xi, 0.f) - xi * yi
                  + __logf(1.f + __expf(-fabsf(xi)));
        tsum += bce;
        psum = fmaf(yi, bce, psum);
        csum += yi;
    }
}

__global__ __launch_bounds__(256, 4) void bce_partial_kernel(
    const float* __restrict__ pred,
    const float* __restrict__ label,
    float*       __restrict__ part,   // [3*nblocks]: pos | tot | cnt
    int n4, int nblocks)
{
    const float4* __restrict__ p4 = (const float4*)pred;
    const float4* __restrict__ y4 = (const float4*)label;

    // block b owns float4 range [b*2048, (b+1)*2048) of each array
    const int lo = blockIdx.x * 2048 + threadIdx.x;   // first half base
    const int hi = lo + 1024;                          // second half base

    float tsum = 0.f, psum = 0.f, csum = 0.f;

    if ((blockIdx.x + 1) * 2048 <= n4) {
        // ---- Phase A: pred[first half]  interleaved with label[second half]
        float4 xa0 = p4[lo];          __builtin_amdgcn_sched_barrier(0);
        float4 lb0 = y4[hi];          __builtin_amdgcn_sched_barrier(0);
        float4 xa1 = p4[lo + 256];    __builtin_amdgcn_sched_barrier(0);
        float4 lb1 = y4[hi + 256];    __builtin_amdgcn_sched_barrier(0);
        float4 xa2 = p4[lo + 512];    __builtin_amdgcn_sched_barrier(0);
        float4 lb2 = y4[hi + 512];    __builtin_amdgcn_sched_barrier(0);
        float4 xa3 = p4[lo + 768];    __builtin_amdgcn_sched_barrier(0);
        float4 lb3 = y4[hi + 768];    __builtin_amdgcn_sched_barrier(0);
        // ---- Phase B: label[first half] interleaved with pred[second half]
        float4 la0 = y4[lo];          __builtin_amdgcn_sched_barrier(0);
        float4 xb0 = p4[hi];          __builtin_amdgcn_sched_barrier(0);
        float4 la1 = y4[lo + 256];    __builtin_amdgcn_sched_barrier(0);
        float4 xb1 = p4[hi + 256];    __builtin_amdgcn_sched_barrier(0);
        float4 la2 = y4[lo + 512];    __builtin_amdgcn_sched_barrier(0);
        float4 xb2 = p4[hi + 512];    __builtin_amdgcn_sched_barrier(0);
        float4 la3 = y4[lo + 768];    __builtin_amdgcn_sched_barrier(0);
        float4 xb3 = p4[hi + 768];    __builtin_amdgcn_sched_barrier(0);

        // first-half pairs (pred from A, label from B)
        bce4(xa0, la0, tsum, psum, csum);
        bce4(xa1, la1, tsum, psum, csum);
        bce4(xa2, la2, tsum, psum, csum);
        bce4(xa3, la3, tsum, psum, csum);
        // second-half pairs (label from A, pred from B)
        bce4(xb0, lb0, tsum, psum, csum);
        bce4(xb1, lb1, tsum, psum, csum);
        bce4(xb2, lb2, tsum, psum, csum);
        bce4(xb3, lb3, tsum, psum, csum);
    } else {
        // ragged tail blocks (dead for n = 16.78M): guarded per-load
#pragma unroll
        for (int k = 0; k < 8; ++k) {
            int i = lo + k * 256;   // covers [lo, lo+2047] in 256 steps
            if (i < n4) {
                float4 xv = p4[i];
                float4 lv = y4[i];
                bce4(xv, lv, tsum, psum, csum);
            }
        }
    }

    // wave-64 reduce
#pragma unroll
    for (int off = 32; off > 0; off >>= 1) {
        tsum += __shfl_down(tsum, off);
        psum += __shfl_down(psum, off);
        csum += __shfl_down(csum, off);
    }

    __shared__ float st[4], sp[4], sc[4];
    const int wave = threadIdx.x >> 6;
    const int lane = threadIdx.x & 63;
    if (lane == 0) { st[wave] = tsum; sp[wave] = psum; sc[wave] = csum; }
    __syncthreads();

    if (threadIdx.x == 0) {
        // plain stores to distinct addresses — no contention, no atomics
        part[blockIdx.x]               = sp[0] + sp[1] + sp[2] + sp[3];
        part[nblocks + blockIdx.x]     = st[0] + st[1] + st[2] + st[3];
        part[2 * nblocks + blockIdx.x] = sc[0] + sc[1] + sc[2] + sc[3];
    }
}

__global__ __launch_bounds__(256) void bce_final_kernel(
    const float* __restrict__ part, int nblocks,
    const float* __restrict__ pred, const float* __restrict__ label,
    int n, float* __restrict__ out)
{
    float psum = 0.f, tsum = 0.f, csum = 0.f;
    for (int i = threadIdx.x; i < nblocks; i += NB_THREADS) {
        psum += part[i];
        tsum += part[nblocks + i];
        csum += part[2 * nblocks + i];
    }
#pragma unroll
    for (int off = 32; off > 0; off >>= 1) {
        psum += __shfl_down(psum, off);
        tsum += __shfl_down(tsum, off);
        csum += __shfl_down(csum, off);
    }
    __shared__ float st[4], sp[4], sc[4];
    const int wave = threadIdx.x >> 6;
    const int lane = threadIdx.x & 63;
    if (lane == 0) { st[wave] = tsum; sp[wave] = psum; sc[wave] = csum; }
    __syncthreads();

    if (threadIdx.x == 0) {
        double pos_sum = (double)(sp[0] + sp[1] + sp[2] + sp[3]);
        double tot_sum = (double)(st[0] + st[1] + st[2] + st[3]);
        double cntf    = (double)(sc[0] + sc[1] + sc[2] + sc[3]);

        // scalar tail (n % 4 != 0) — dead for n = 16M
        const int n4 = n >> 2;
        for (int r = (n4 << 2); r < n; ++r) {
            float xi = pred[r], yi = label[r];
            float bce = fmaxf(xi, 0.f) - xi * yi
                      + __logf(1.f + __expf(-fabsf(xi)));
            tot_sum += bce;
            pos_sum += (double)yi * bce;
            cntf    += yi;
        }

        long long num_pos = (long long)(cntf + 0.5);
        long long num_neg = (long long)n - num_pos;
        long long least   = (long long)((double)n * 0.05); // int(n*0.05)
        long long K = 3LL * num_pos;
        if (K < least)   K = least;
        if (K > num_neg) K = num_neg;

        double neg_sum = tot_sum - pos_sum;
        double sel = (num_neg > 0) ? ((double)K * neg_sum / (double)num_neg) : 0.0;
        double denom = (double)num_pos + (double)K;
        out[0] = (float)((denom > 0.0) ? ((pos_sum + sel) / denom) : 0.0);
    }
}

extern "C" void kernel_launch(void* const* d_in, const int* in_sizes, int n_in,
                              void* d_out, int out_size, void* d_ws, size_t ws_size,
                              hipStream_t stream)
{
    const float* pred  = (const float*)d_in[0];
    const float* label = (const float*)d_in[1];
    const int n = in_sizes[0];
    const int n4 = n >> 2;

    // each block covers 2048 float4 = 8192 elements of each array
    int nblocks = (n4 + 2047) / 2048;              // 2048 for n = 16.78M
    if (nblocks < 1) nblocks = 1;                  // tiny-n safety

    float* part = (float*)d_ws;                    // 3 * nblocks floats

    bce_partial_kernel<<<nblocks, NB_THREADS, 0, stream>>>(pred, label, part,
                                                           n4, nblocks);
    bce_final_kernel<<<1, NB_THREADS, 0, stream>>>(part, nblocks, pred, label,
                                                   n, (float*)d_out);
}